// Round 4
// baseline (624.800 us; speedup 1.0000x reference)
//
#include <hip/hip_runtime.h>

typedef unsigned int uint;
typedef unsigned short ushort;
typedef __attribute__((ext_vector_type(8))) short bf16x8;
typedef __attribute__((ext_vector_type(4))) float f32x4;

#define GLD_LDS(g, l) __builtin_amdgcn_global_load_lds( \
    (const __attribute__((address_space(1))) void*)(g), \
    (__attribute__((address_space(3))) void*)(l), 16, 0, 0)

__device__ __forceinline__ ushort f2bf(float f) {
    uint u = __builtin_bit_cast(uint, f);
    u += 0x7fffu + ((u >> 16) & 1u);
    return (ushort)(u >> 16);
}
__device__ __forceinline__ float bf2f(ushort s) {
    uint u = ((uint)s) << 16;
    return __builtin_bit_cast(float, u);
}
__device__ __forceinline__ void wave_sync() {
    asm volatile("s_waitcnt lgkmcnt(0)" ::: "memory");
}
__device__ __forceinline__ float wave_max(float v) {
#pragma unroll
    for (int d = 32; d >= 1; d >>= 1) v = fmaxf(v, __shfl_xor(v, d));
    return v;
}
__device__ __forceinline__ float wave_sum(float v) {
#pragma unroll
    for (int d = 32; d >= 1; d >>= 1) v += __shfl_xor(v, d);
    return v;
}

// ---------------- CSR build ----------------
__global__ void deg_kernel(const int* __restrict__ dst, int* __restrict__ cnt, int E) {
    int e = blockIdx.x * 256 + threadIdx.x;
    if (e < E) atomicAdd(&cnt[dst[e]], 1);
}

__global__ void scan_kernel(const int* __restrict__ cnt, int* __restrict__ offs, int n) {
    __shared__ int part[1024];
    const int t = threadIdx.x;
    const int strip = (n + 1023) / 1024;
    int s = 0;
    for (int i = 0; i < strip; ++i) {
        int idx = t * strip + i;
        if (idx < n) s += cnt[idx];
    }
    part[t] = s;
    __syncthreads();
    for (int d = 1; d < 1024; d <<= 1) {
        int v = (t >= d) ? part[t - d] : 0;
        __syncthreads();
        part[t] += v;
        __syncthreads();
    }
    int run = (t == 0) ? 0 : part[t - 1];
    for (int i = 0; i < strip; ++i) {
        int idx = t * strip + i;
        if (idx < n) { offs[idx] = run; run += cnt[idx]; }
    }
    if (t == 1023) offs[n] = part[1023];
}

__global__ void fill_kernel(const int* __restrict__ dst, const int* __restrict__ offs,
                            int* __restrict__ cur, int* __restrict__ csr, int E) {
    int e = blockIdx.x * 256 + threadIdx.x;
    if (e < E) {
        int d = dst[e];
        int p = offs[d] + atomicAdd(&cur[d], 1);
        csr[p] = e;
    }
}

__global__ void hole_kernel(const int* __restrict__ bat, int* __restrict__ hole, int N) {
    int n = blockIdx.x * 256 + threadIdx.x;
    if (n < N) atomicMin(&hole[bat[n]], n);
}

// ---------------- weight prep ----------------
__global__ void trW_kernel(const float* __restrict__ W, ushort* __restrict__ Wt,
                           int cin, int ho, long total) {
    long idx = (long)blockIdx.x * 256 + threadIdx.x;
    if (idx >= total) return;
    long ncol = idx / cin;
    int c = (int)(idx % cin);
    int r = (int)(ncol / ho);
    int o = (int)(ncol % ho);
    Wt[idx] = f2bf(W[((long)r * cin + c) * ho + o]);
}

__global__ void trLw_kernel(const float* __restrict__ lw, ushort* __restrict__ lwT,
                            int cout_in, long total) {
    long idx = (long)blockIdx.x * 256 + threadIdx.x;
    if (idx >= total) return;
    int o = (int)(idx / cout_in);
    int c = (int)(idx % cout_in);
    lwT[idx] = f2bf(lw[(long)c * 256 + o]);
}

// A2[j][o] = W2[r][c][h*384+o] / 3, j = h*1024 + r*256 + c   (3072 x 384 bf16)
__global__ void a2_kernel(const float* __restrict__ W2, ushort* __restrict__ A2) {
    long idx = (long)blockIdx.x * 256 + threadIdx.x;
    if (idx >= 3072L * 384) return;
    int j = (int)(idx / 384), o = (int)(idx % 384);
    int h = j >> 10, rc = j & 1023;
    int r = rc >> 8, c = rc & 255;
    A2[idx] = f2bf(W2[((long)(r * 256 + c)) * 1152 + h * 384 + o] * (1.f / 3.f));
}

// bf2[o2] = sum_o b2[o]*lw2[o][o2] + lb2[o2]   (256 outputs, one wave each)
__global__ __launch_bounds__(256)
void bfold_kernel(const float* __restrict__ b2, const float* __restrict__ lw2,
                  const float* __restrict__ lb2, float* __restrict__ bf2) {
    const int wid = threadIdx.x >> 6, lane = threadIdx.x & 63;
    const int o2 = blockIdx.x * 4 + wid;
    if (o2 >= 256) return;
    float s = 0.f;
    for (int o = lane; o < 384; o += 64) s += b2[o] * lw2[(long)o * 256 + o2];
    s = wave_sum(s);
    if (lane == 0) bf2[o2] = s + lb2[o2];
}

__global__ void g_kernel(const float* __restrict__ le, const float* __restrict__ e,
                         float* __restrict__ g, int ho) {
    int j = blockIdx.x;
    int d = j / 3, h = j % 3;
    float s = 0.f;
    for (int o = threadIdx.x; o < ho; o += 64) s += le[(long)d * ho + o] * e[(long)o * 3 + h];
    s = wave_sum(s);
    if (threadIdx.x == 0) g[j] = s;
}

__global__ void ae_kernel(const float* __restrict__ ea, const float* __restrict__ g,
                          float* __restrict__ aeb, int E) {
    int e = blockIdx.x * 256 + threadIdx.x;
    if (e >= E) return;
    float a[8];
#pragma unroll
    for (int d = 0; d < 8; ++d) a[d] = ea[(long)e * 8 + d];
#pragma unroll
    for (int l = 0; l < 4; ++l) {
#pragma unroll
        for (int h = 0; h < 3; ++h) {
            float s = 0.f;
#pragma unroll
            for (int d = 0; d < 8; ++d) s += a[d] * g[l * 24 + d * 3 + h];
            aeb[((size_t)l * E + e) * 3 + h] = s;
        }
    }
}

// one WAVE per output element; 64-lane coalesced reduce over o
__global__ __launch_bounds__(256)
void wqk_kernel(const float* __restrict__ W, const float* __restrict__ q,
                const float* __restrict__ k, float* __restrict__ Wqk,
                int cin, int ho) {
    const int wid = threadIdx.x >> 6, lane = threadIdx.x & 63;
    const int i = blockIdx.x * 4 + wid;
    if (i >= cin * 24) return;
    int c = i / 24, j = i % 24;
    int r = j / 6, t6 = j % 6;
    const float* v = (t6 < 3) ? q : k;
    int h = t6 % 3;
    const float* wrow = W + ((long)r * cin + c) * ho;
    float s = 0.f;
    for (int o = lane; o < ho; o += 64) s += wrow[o] * v[(long)o * 3 + h];
    s = wave_sum(s);
    if (lane == 0) Wqk[i] = s;
}

__global__ __launch_bounds__(256)
void qk_kernel(const float* __restrict__ h, const float* __restrict__ Wqk,
               float* __restrict__ qkn, int N, int cin) {
    const int wid = threadIdx.x >> 6, lane = threadIdx.x & 63;
    const int n = blockIdx.x * 4 + wid;
    if (n >= N) return;
    float acc[24];
#pragma unroll
    for (int j = 0; j < 24; ++j) acc[j] = 0.f;
    for (int c = lane; c < cin; c += 64) {
        float hv = h[(long)n * cin + c];
        const float* w = Wqk + (long)c * 24;
#pragma unroll
        for (int j = 0; j < 24; ++j) acc[j] += hv * w[j];
    }
#pragma unroll
    for (int j = 0; j < 24; ++j) {
        float v = wave_sum(acc[j]);
        if (lane == 0) qkn[(long)n * 24 + j] = v;
    }
}

// ---------------- cast fp32 -> bf16 ----------------
__global__ void cast_kernel(const float* __restrict__ in, ushort* __restrict__ out, long n) {
    long i = ((long)blockIdx.x * 256 + threadIdx.x) * 4;
    if (i + 4 <= n) {
        float4 v = *(const float4*)(in + i);
        ushort4 o4 = { f2bf(v.x), f2bf(v.y), f2bf(v.z), f2bf(v.w) };
        *(ushort4*)(out + i) = o4;
    } else {
        for (long j = i; j < n; ++j) out[j] = f2bf(in[j]);
    }
}

// ---------------- bf16 MFMA GEMM: C(M,NCols) = A(M,K) * Bt(NCols,K)^T ----------------
template<int OUT_BF16, int DUAL>
__global__ __launch_bounds__(256, 2)
void gemm_bf16(const ushort* __restrict__ A, const ushort* __restrict__ Bt,
               void* __restrict__ Cp, ushort* __restrict__ C2,
               const float* __restrict__ bias,
               int M, int K, int NCols, int nbn, int nwg) {
    __shared__ ushort lA[128 * 32];
    __shared__ ushort lB[128 * 32];
    const int t = threadIdx.x;
    const int lane = t & 63;
    const int wid = t >> 6;

    int b = blockIdx.x;
    int q8 = nwg >> 3, r8 = nwg & 7;
    int xcd = b & 7, loc = b >> 3;
    int tile = (xcd < r8 ? xcd * (q8 + 1) : r8 * (q8 + 1) + (xcd - r8) * q8) + loc;
    const int bm = (tile / nbn) * 128;
    const int bn = (tile % nbn) * 128;

    const int wr = (wid >> 1) * 64;
    const int wc = (wid & 1) * 64;

    f32x4 acc[4][4];
#pragma unroll
    for (int m = 0; m < 4; ++m)
#pragma unroll
        for (int nn = 0; nn < 4; ++nn) acc[m][nn] = (f32x4){0.f, 0.f, 0.f, 0.f};

    const int sr = t >> 2;
    const int sk = (((t & 3) ^ ((t >> 3) & 3)) * 8);
    long ar0 = bm + sr;      if (ar0 > M - 1) ar0 = M - 1;
    long ar1 = bm + sr + 64; if (ar1 > M - 1) ar1 = M - 1;
    const ushort* gA0 = A + ar0 * K + sk;
    const ushort* gA1 = A + ar1 * K + sk;
    const ushort* gB0 = Bt + (long)(bn + sr) * K + sk;
    const ushort* gB1 = Bt + (long)(bn + sr + 64) * K + sk;
    ushort* sA0 = &lA[t * 8];
    ushort* sA1 = &lA[t * 8 + 64 * 32];
    ushort* sB0 = &lB[t * 8];
    ushort* sB1 = &lB[t * 8 + 64 * 32];

    const int frow = lane & 15;
    const int pc8 = (((lane >> 4) ^ ((lane >> 1) & 3)) * 8);

    for (int k0 = 0; k0 < K; k0 += 32) {
        GLD_LDS(gA0 + k0, sA0);
        GLD_LDS(gA1 + k0, sA1);
        GLD_LDS(gB0 + k0, sB0);
        GLD_LDS(gB1 + k0, sB1);
        __syncthreads();
        bf16x8 af[4], bff[4];
#pragma unroll
        for (int m = 0; m < 4; ++m)
            af[m] = *(const bf16x8*)&lA[(wr + m * 16 + frow) * 32 + pc8];
#pragma unroll
        for (int nn = 0; nn < 4; ++nn)
            bff[nn] = *(const bf16x8*)&lB[(wc + nn * 16 + frow) * 32 + pc8];
#pragma unroll
        for (int m = 0; m < 4; ++m)
#pragma unroll
            for (int nn = 0; nn < 4; ++nn)
                acc[m][nn] = __builtin_amdgcn_mfma_f32_16x16x32_bf16(af[m], bff[nn], acc[m][nn], 0, 0, 0);
        __syncthreads();
    }

    const int crow = (lane >> 4) * 4;
    const int ccol = lane & 15;
#pragma unroll
    for (int m = 0; m < 4; ++m) {
#pragma unroll
        for (int nn = 0; nn < 4; ++nn) {
            int col = bn + wc + nn * 16 + ccol;
            float bv = bias ? bias[col] : 0.f;
#pragma unroll
            for (int r = 0; r < 4; ++r) {
                int row = bm + wr + m * 16 + crow + r;
                if (row < M) {
                    float v = acc[m][nn][r] + bv;
                    if (OUT_BF16) ((ushort*)Cp)[(long)row * NCols + col] = f2bf(v);
                    else          ((float*)Cp)[(long)row * NCols + col] = v;
                    if (DUAL)     C2[(long)row * NCols + col] = f2bf(v);
                }
            }
        }
    }
}

// ---------------- attention + aggregate (layers 1,3,4: one wave per node) ----------------
template<int CP, int OO>
__global__ __launch_bounds__(256)
void attn_kernel(const float* __restrict__ qkn, const ushort* __restrict__ xW,
                 const float* __restrict__ ae, const int* __restrict__ offs,
                 const int* __restrict__ csr, const int* __restrict__ srcv,
                 const int* __restrict__ etv, const float* __restrict__ bias,
                 ushort* __restrict__ out, int N) {
    __shared__ float p_sh[4][64][3];
    __shared__ int   m_sh[4][64];
    __shared__ float red[4][CP * 128];
    const int wid = threadIdx.x >> 6, lane = threadIdx.x & 63;
    const int n = blockIdx.x * 4 + wid;
    if (n >= N) return;
    const int e0 = offs[n];
    const int deg = offs[n + 1] - e0;
    const float* qd = qkn + (long)n * 24;

    float m0 = -1e30f, m1 = -1e30f, m2 = -1e30f;
    for (int base = 0; base < deg; base += 64) {
        int idx = base + lane;
        if (idx < deg) {
            int eid = csr[e0 + idx];
            int s_ = srcv[eid], t_ = etv[eid];
            const float* qs = qkn + (long)s_ * 24 + t_ * 6;
            const float* a3 = ae + (long)eid * 3;
            float v0 = qd[t_ * 6 + 0] + qs[3] + a3[0];
            float v1 = qd[t_ * 6 + 1] + qs[4] + a3[1];
            float v2 = qd[t_ * 6 + 2] + qs[5] + a3[2];
            v0 = v0 > 0.f ? v0 : 0.2f * v0;
            v1 = v1 > 0.f ? v1 : 0.2f * v1;
            v2 = v2 > 0.f ? v2 : 0.2f * v2;
            m0 = fmaxf(m0, v0); m1 = fmaxf(m1, v1); m2 = fmaxf(m2, v2);
        }
    }
    m0 = wave_max(m0); m1 = wave_max(m1); m2 = wave_max(m2);

    float acc[2 * CP];
#pragma unroll
    for (int i = 0; i < 2 * CP; ++i) acc[i] = 0.f;
    float ps0 = 0.f, ps1 = 0.f, ps2 = 0.f;

    for (int base = 0; base < deg; base += 64) {
        int cnt2 = deg - base; if (cnt2 > 64) cnt2 = 64;
        if (lane < cnt2) {
            int eid = csr[e0 + base + lane];
            int s_ = srcv[eid], t_ = etv[eid];
            const float* qs = qkn + (long)s_ * 24 + t_ * 6;
            const float* a3 = ae + (long)eid * 3;
            float v0 = qd[t_ * 6 + 0] + qs[3] + a3[0];
            float v1 = qd[t_ * 6 + 1] + qs[4] + a3[1];
            float v2 = qd[t_ * 6 + 2] + qs[5] + a3[2];
            v0 = v0 > 0.f ? v0 : 0.2f * v0;
            v1 = v1 > 0.f ? v1 : 0.2f * v1;
            v2 = v2 > 0.f ? v2 : 0.2f * v2;
            float p0 = __expf(v0 - m0), p1 = __expf(v1 - m1), p2 = __expf(v2 - m2);
            p_sh[wid][lane][0] = p0; p_sh[wid][lane][1] = p1; p_sh[wid][lane][2] = p2;
            m_sh[wid][lane] = (s_ * 4 + t_) * (CP * 128);
            ps0 += p0; ps1 += p1; ps2 += p2;
        }
        wave_sync();
        for (int j = 0; j < cnt2; ++j) {
            int xb = m_sh[wid][j];
            float pp0 = p_sh[wid][j][0], pp1 = p_sh[wid][j][1], pp2 = p_sh[wid][j][2];
            const uint* xr = (const uint*)(xW + xb);
#pragma unroll
            for (int ii = 0; ii < CP; ++ii) {
                uint v = xr[lane + 64 * ii];
                const int hh = (ii * 128) / OO;
                float p = (hh == 0) ? pp0 : (hh == 1 ? pp1 : pp2);
                acc[2 * ii]     += p * bf2f((ushort)(v & 0xffffu));
                acc[2 * ii + 1] += p * bf2f((ushort)(v >> 16));
            }
        }
        wave_sync();
    }
    ps0 = wave_sum(ps0); ps1 = wave_sum(ps1); ps2 = wave_sum(ps2);
    float i0 = 1.f / fmaxf(ps0, 1e-16f);
    float i1 = 1.f / fmaxf(ps1, 1e-16f);
    float i2 = 1.f / fmaxf(ps2, 1e-16f);
#pragma unroll
    for (int ii = 0; ii < CP; ++ii) {
        const int hh = (ii * 128) / OO;
        float iv = (hh == 0) ? i0 : (hh == 1 ? i1 : i2);
        red[wid][128 * ii + 2 * lane]     = acc[2 * ii] * iv;
        red[wid][128 * ii + 2 * lane + 1] = acc[2 * ii + 1] * iv;
    }
    wave_sync();
    for (int o = lane; o < OO; o += 64) {
        float v = (red[wid][o] + red[wid][OO + o] + red[wid][2 * OO + o]) * (1.f / 3.f) + bias[o];
        out[(long)n * OO + o] = f2bf(v);
    }
}

// ---------------- layer-2 attention: Z-accumulation (one wave per node) ----------------
// Z[n][h*1024 + r*256 + c] = (1/ps_h) * sum_{j: et=r} p_{j,h} * hbf[src_j][c]
#define UPD(R) { \
    acc[0][R][0] += pk.x * x0; acc[0][R][1] += pk.x * x1; acc[0][R][2] += pk.x * x2; acc[0][R][3] += pk.x * x3; \
    acc[1][R][0] += pk.y * x0; acc[1][R][1] += pk.y * x1; acc[1][R][2] += pk.y * x2; acc[1][R][3] += pk.y * x3; \
    acc[2][R][0] += pk.z * x0; acc[2][R][1] += pk.z * x1; acc[2][R][2] += pk.z * x2; acc[2][R][3] += pk.z * x3; }

__global__ __launch_bounds__(256)
void attn2_kernel(const float* __restrict__ qkn, const ushort* __restrict__ hbf,
                  const float* __restrict__ ae, const int* __restrict__ offs,
                  const int* __restrict__ csr, const int* __restrict__ srcv,
                  const int* __restrict__ etv, ushort* __restrict__ Z, int N) {
    __shared__ float4 pk_sh[4][64];
    const int wid = threadIdx.x >> 6, lane = threadIdx.x & 63;
    const int n = blockIdx.x * 4 + wid;
    if (n >= N) return;
    const int e0 = offs[n];
    const int deg = offs[n + 1] - e0;
    const float* qd = qkn + (long)n * 24;

    float m0 = -1e30f, m1 = -1e30f, m2 = -1e30f;
    for (int base = 0; base < deg; base += 64) {
        int idx = base + lane;
        if (idx < deg) {
            int eid = csr[e0 + idx];
            int s_ = srcv[eid], t_ = etv[eid];
            const float* qs = qkn + (long)s_ * 24 + t_ * 6;
            const float* a3 = ae + (long)eid * 3;
            float v0 = qd[t_ * 6 + 0] + qs[3] + a3[0];
            float v1 = qd[t_ * 6 + 1] + qs[4] + a3[1];
            float v2 = qd[t_ * 6 + 2] + qs[5] + a3[2];
            v0 = v0 > 0.f ? v0 : 0.2f * v0;
            v1 = v1 > 0.f ? v1 : 0.2f * v1;
            v2 = v2 > 0.f ? v2 : 0.2f * v2;
            m0 = fmaxf(m0, v0); m1 = fmaxf(m1, v1); m2 = fmaxf(m2, v2);
        }
    }
    m0 = wave_max(m0); m1 = wave_max(m1); m2 = wave_max(m2);

    float acc[3][4][4];
#pragma unroll
    for (int h = 0; h < 3; ++h)
#pragma unroll
        for (int r = 0; r < 4; ++r)
#pragma unroll
            for (int c = 0; c < 4; ++c) acc[h][r][c] = 0.f;
    float ps0 = 0.f, ps1 = 0.f, ps2 = 0.f;

    for (int base = 0; base < deg; base += 64) {
        int cnt2 = deg - base; if (cnt2 > 64) cnt2 = 64;
        if (lane < cnt2) {
            int eid = csr[e0 + base + lane];
            int s_ = srcv[eid], t_ = etv[eid];
            const float* qs = qkn + (long)s_ * 24 + t_ * 6;
            const float* a3 = ae + (long)eid * 3;
            float v0 = qd[t_ * 6 + 0] + qs[3] + a3[0];
            float v1 = qd[t_ * 6 + 1] + qs[4] + a3[1];
            float v2 = qd[t_ * 6 + 2] + qs[5] + a3[2];
            v0 = v0 > 0.f ? v0 : 0.2f * v0;
            v1 = v1 > 0.f ? v1 : 0.2f * v1;
            v2 = v2 > 0.f ? v2 : 0.2f * v2;
            float p0 = __expf(v0 - m0), p1 = __expf(v1 - m1), p2 = __expf(v2 - m2);
            pk_sh[wid][lane] = make_float4(p0, p1, p2,
                                           __int_as_float((s_ << 2) | t_));
            ps0 += p0; ps1 += p1; ps2 += p2;
        }
        wave_sync();
        for (int j = 0; j < cnt2; ++j) {
            float4 pk = pk_sh[wid][j];
            int pack = __float_as_int(pk.w);
            int r_ = pack & 3;
            const uint2 v = *(const uint2*)(hbf + ((long)(pack >> 2)) * 256 + lane * 4);
            float x0 = bf2f((ushort)(v.x & 0xffffu)), x1 = bf2f((ushort)(v.x >> 16));
            float x2 = bf2f((ushort)(v.y & 0xffffu)), x3 = bf2f((ushort)(v.y >> 16));
            if (r_ == 0)      UPD(0)
            else if (r_ == 1) UPD(1)
            else if (r_ == 2) UPD(2)
            else              UPD(3)
        }
        wave_sync();
    }
    ps0 = wave_sum(ps0); ps1 = wave_sum(ps1); ps2 = wave_sum(ps2);
    float inv[3];
    inv[0] = 1.f / fmaxf(ps0, 1e-16f);
    inv[1] = 1.f / fmaxf(ps1, 1e-16f);
    inv[2] = 1.f / fmaxf(ps2, 1e-16f);
    ushort* zr = Z + (long)n * 3072 + lane * 4;
#pragma unroll
    for (int h = 0; h < 3; ++h) {
#pragma unroll
        for (int r = 0; r < 4; ++r) {
            ushort4 o4 = { f2bf(acc[h][r][0] * inv[h]), f2bf(acc[h][r][1] * inv[h]),
                           f2bf(acc[h][r][2] * inv[h]), f2bf(acc[h][r][3] * inv[h]) };
            *(ushort4*)(zr + h * 1024 + r * 256) = o4;
        }
    }
}

// ---------------- final: hole-node softmax ----------------
__global__ void softmax_kernel(const float* __restrict__ h, const int* __restrict__ hole,
                               float* __restrict__ out, int B) {
    int b = blockIdx.x;
    int t = threadIdx.x;
    int lane = t & 63, wid = t >> 6;
    __shared__ float sm[4];
    __shared__ float ss[4];
    int row = hole[b];
    float v = h[(long)row * 256 + t];
    float m = v;
#pragma unroll
    for (int d = 32; d >= 1; d >>= 1) m = fmaxf(m, __shfl_xor(m, d));
    if (lane == 0) sm[wid] = m;
    __syncthreads();
    m = fmaxf(fmaxf(sm[0], sm[1]), fmaxf(sm[2], sm[3]));
    float ex = __expf(v - m);
    float s = ex;
#pragma unroll
    for (int d = 32; d >= 1; d >>= 1) s += __shfl_xor(s, d);
    if (lane == 0) ss[wid] = s;
    __syncthreads();
    s = ss[0] + ss[1] + ss[2] + ss[3];
    out[(long)b * 256 + t] = ex / s;
}

// ---------------- host ----------------
extern "C" void kernel_launch(void* const* d_in, const int* in_sizes, int n_in,
                              void* d_out, int out_size, void* d_ws, size_t ws_size,
                              hipStream_t stream) {
    const float* x   = (const float*)d_in[0];
    const int*   ei  = (const int*)d_in[1];
    const int*   ety = (const int*)d_in[2];
    const float* ea  = (const float*)d_in[3];
    const int*   bat = (const int*)d_in[4];

    const int N = in_sizes[0] / 768;
    const int E = in_sizes[2];
    const int B = out_size / 256;

    static const int CIN[4]  = {768, 256, 256, 256};
    static const int COUT[4] = {128, 384, 128, 128};
    static const int HO[4]   = {384, 1152, 384, 384};
    static const int NCC[4]  = {1536, 4608, 1536, 1536};

    const float *Wp[4], *qp[4], *kp[4], *lep[4], *ep[4], *bp[4], *lwp[4], *lbp[4];
    for (int l = 0; l < 4; ++l) {
        Wp[l]  = (const float*)d_in[5 + 6 * l];
        qp[l]  = (const float*)d_in[6 + 6 * l];
        kp[l]  = (const float*)d_in[7 + 6 * l];
        lep[l] = (const float*)d_in[8 + 6 * l];
        ep[l]  = (const float*)d_in[9 + 6 * l];
        bp[l]  = (const float*)d_in[10 + 6 * l];
        lwp[l] = (const float*)d_in[29 + 2 * l];
        lbp[l] = (const float*)d_in[30 + 2 * l];
    }

    char* ws = (char*)d_ws;
    size_t pos = 0;
    auto carve = [&](size_t bytes) -> char* {
        char* r = ws + pos;
        pos += (bytes + 255) & ~(size_t)255;
        return r;
    };
    ushort *Wt[4], *lwT[4];
    float* Wqk[4];
    for (int l = 0; l < 4; ++l) Wt[l]  = (ushort*)carve(l == 1 ? 0 : (size_t)2 * NCC[l] * CIN[l]);
    for (int l = 0; l < 4; ++l) lwT[l] = (ushort*)carve((size_t)2 * 256 * COUT[l]);
    for (int l = 0; l < 4; ++l) Wqk[l] = (float*)carve((size_t)4 * 24 * CIN[l]);
    float*  gbuf  = (float*)carve(4 * 24 * 4);
    float*  aeb   = (float*)carve((size_t)4 * E * 3 * 4);
    float*  qkn   = (float*)carve((size_t)N * 24 * 4);
    ushort* hbf   = (ushort*)carve((size_t)N * 768 * 2);
    ushort* xWb   = (ushort*)carve((size_t)N * 1536 * 2);
    ushort* Zb    = (ushort*)carve((size_t)N * 3072 * 2);
    ushort* A2    = (ushort*)carve((size_t)3072 * 384 * 2);
    ushort* W2T   = (ushort*)carve((size_t)256 * 3072 * 2);
    float*  bf2   = (float*)carve(256 * 4);
    ushort* convbf= (ushort*)carve((size_t)N * 384 * 2);
    float*  hbuf  = (float*)carve((size_t)N * 256 * 4);
    int* cnt  = (int*)carve((size_t)N * 4);
    int* offs = (int*)carve((size_t)(N + 1) * 4);
    int* cur  = (int*)carve((size_t)N * 4);
    int* csr  = (int*)carve((size_t)E * 4);
    int* hole = (int*)carve((size_t)B * 4);

    hipMemsetAsync(cnt, 0, (size_t)N * 4, stream);
    hipMemsetAsync(cur, 0, (size_t)N * 4, stream);
    hipMemsetAsync(hole, 0x7f, (size_t)B * 4, stream);

    const int* dst = ei + E;
    deg_kernel<<<(E + 255) / 256, 256, 0, stream>>>(dst, cnt, E);
    scan_kernel<<<1, 1024, 0, stream>>>(cnt, offs, N);
    fill_kernel<<<(E + 255) / 256, 256, 0, stream>>>(dst, offs, cur, csr, E);
    hole_kernel<<<(N + 255) / 256, 256, 0, stream>>>(bat, hole, N);

    for (int l = 0; l < 4; ++l) {
        if (l != 1) {
            long tw = (long)NCC[l] * CIN[l];
            trW_kernel<<<(int)((tw + 255) / 256), 256, 0, stream>>>(Wp[l], Wt[l], CIN[l], HO[l], tw);
        }
        long tl = 256L * COUT[l];
        trLw_kernel<<<(int)((tl + 255) / 256), 256, 0, stream>>>(lwp[l], lwT[l], COUT[l], tl);
        g_kernel<<<24, 64, 0, stream>>>(lep[l], ep[l], gbuf + l * 24, HO[l]);
        wqk_kernel<<<(CIN[l] * 24 + 3) / 4, 256, 0, stream>>>(Wp[l], qp[l], kp[l], Wqk[l], CIN[l], HO[l]);
    }
    // layer-2 fold: W2T(256,3072) = lwT2(256,384) @ A2(3072,384)^T ; bf2 = b2@lw2 + lb2
    a2_kernel<<<(int)((3072L * 384 + 255) / 256), 256, 0, stream>>>(Wp[1], A2);
    gemm_bf16<1, 0><<<48, 256, 0, stream>>>(lwT[1], A2, (void*)W2T, nullptr, nullptr,
                                            256, 384, 3072, 24, 48);
    bfold_kernel<<<64, 256, 0, stream>>>(bp[1], lwp[1], lbp[1], bf2);
    ae_kernel<<<(E + 255) / 256, 256, 0, stream>>>(ea, gbuf, aeb, E);

    const int nbm = (N + 127) / 128;
    for (int l = 0; l < 4; ++l) {
        const float* hin = (l == 0) ? x : hbuf;
        if (l == 0) {
            long hc = (long)N * 768;
            cast_kernel<<<(int)((hc / 4 + 255) / 256), 256, 0, stream>>>(x, hbf, hc);
        }
        qk_kernel<<<(N + 3) / 4, 256, 0, stream>>>(hin, Wqk[l], qkn, N, CIN[l]);
        if (l == 1) {
            attn2_kernel<<<(N + 3) / 4, 256, 0, stream>>>(qkn, hbf, aeb + (size_t)l * E * 3,
                                                          offs, csr, ei, ety, Zb, N);
            int nwg2 = nbm * 2;
            gemm_bf16<0, 1><<<nwg2, 256, 0, stream>>>(Zb, W2T, (void*)hbuf, hbf, bf2,
                                                      N, 3072, 256, 2, nwg2);
        } else {
            int nbn1 = NCC[l] / 128, nwg1 = nbm * nbn1;
            gemm_bf16<1, 0><<<nwg1, 256, 0, stream>>>(hbf, Wt[l], (void*)xWb, nullptr, nullptr,
                                                      N, CIN[l], NCC[l], nbn1, nwg1);
            attn_kernel<3, 128><<<(N + 3) / 4, 256, 0, stream>>>(qkn, xWb, aeb + (size_t)l * E * 3,
                                                                 offs, csr, ei, ety, bp[l], convbf, N);
            int nwg2 = nbm * 2;
            gemm_bf16<0, 1><<<nwg2, 256, 0, stream>>>(convbf, lwT[l], (void*)hbuf, hbf, lbp[l],
                                                      N, COUT[l], 256, 2, nwg2);
        }
    }
    softmax_kernel<<<B, 256, 0, stream>>>(hbuf, hole, (float*)d_out, B);
}

// Round 5
// 594.164 us; speedup vs baseline: 1.0516x; 1.0516x over previous
//
#include <hip/hip_runtime.h>

typedef unsigned int uint;
typedef unsigned short ushort;
typedef __attribute__((ext_vector_type(8))) short bf16x8;
typedef __attribute__((ext_vector_type(4))) float f32x4;

#define GLD_LDS(g, l) __builtin_amdgcn_global_load_lds( \
    (const __attribute__((address_space(1))) void*)(g), \
    (__attribute__((address_space(3))) void*)(l), 16, 0, 0)

__device__ __forceinline__ ushort f2bf(float f) {
    uint u = __builtin_bit_cast(uint, f);
    u += 0x7fffu + ((u >> 16) & 1u);
    return (ushort)(u >> 16);
}
__device__ __forceinline__ float bf2f(ushort s) {
    uint u = ((uint)s) << 16;
    return __builtin_bit_cast(float, u);
}
__device__ __forceinline__ void wave_sync() {
    asm volatile("s_waitcnt lgkmcnt(0)" ::: "memory");
}
__device__ __forceinline__ float wave_max(float v) {
#pragma unroll
    for (int d = 32; d >= 1; d >>= 1) v = fmaxf(v, __shfl_xor(v, d));
    return v;
}
__device__ __forceinline__ float wave_sum(float v) {
#pragma unroll
    for (int d = 32; d >= 1; d >>= 1) v += __shfl_xor(v, d);
    return v;
}

// ---------------- CSR build ----------------
__global__ void deg_kernel(const int* __restrict__ dst, int* __restrict__ cnt, int E) {
    int e = blockIdx.x * 256 + threadIdx.x;
    if (e < E) atomicAdd(&cnt[dst[e]], 1);
}

__global__ void scan_kernel(const int* __restrict__ cnt, int* __restrict__ offs, int n) {
    __shared__ int part[1024];
    const int t = threadIdx.x;
    const int strip = (n + 1023) / 1024;
    int s = 0;
    for (int i = 0; i < strip; ++i) {
        int idx = t * strip + i;
        if (idx < n) s += cnt[idx];
    }
    part[t] = s;
    __syncthreads();
    for (int d = 1; d < 1024; d <<= 1) {
        int v = (t >= d) ? part[t - d] : 0;
        __syncthreads();
        part[t] += v;
        __syncthreads();
    }
    int run = (t == 0) ? 0 : part[t - 1];
    for (int i = 0; i < strip; ++i) {
        int idx = t * strip + i;
        if (idx < n) { offs[idx] = run; run += cnt[idx]; }
    }
    if (t == 1023) offs[n] = part[1023];
}

__global__ void fill_kernel(const int* __restrict__ dst, const int* __restrict__ offs,
                            int* __restrict__ cur, int* __restrict__ csr, int E) {
    int e = blockIdx.x * 256 + threadIdx.x;
    if (e < E) {
        int d = dst[e];
        int p = offs[d] + atomicAdd(&cur[d], 1);
        csr[p] = e;
    }
}

__global__ void hole_kernel(const int* __restrict__ bat, int* __restrict__ hole, int N) {
    int n = blockIdx.x * 256 + threadIdx.x;
    if (n < N) atomicMin(&hole[bat[n]], n);
}

// ---------------- weight prep ----------------
__global__ void trW_kernel(const float* __restrict__ W, ushort* __restrict__ Wt,
                           int cin, int ho, long total) {
    long idx = (long)blockIdx.x * 256 + threadIdx.x;
    if (idx >= total) return;
    long ncol = idx / cin;
    int c = (int)(idx % cin);
    int r = (int)(ncol / ho);
    int o = (int)(ncol % ho);
    Wt[idx] = f2bf(W[((long)r * cin + c) * ho + o]);
}

__global__ void trLw_kernel(const float* __restrict__ lw, ushort* __restrict__ lwT,
                            int cout_in, long total) {
    long idx = (long)blockIdx.x * 256 + threadIdx.x;
    if (idx >= total) return;
    int o = (int)(idx / cout_in);
    int c = (int)(idx % cout_in);
    lwT[idx] = f2bf(lw[(long)c * 256 + o]);
}

// A2[j][o] = W2[r][c][h*384+o] / 3, j = h*1024 + r*256 + c   (3072 x 384 bf16)
__global__ void a2_kernel(const float* __restrict__ W2, ushort* __restrict__ A2) {
    long idx = (long)blockIdx.x * 256 + threadIdx.x;
    if (idx >= 3072L * 384) return;
    int j = (int)(idx / 384), o = (int)(idx % 384);
    int h = j >> 10, rc = j & 1023;
    int r = rc >> 8, c = rc & 255;
    A2[idx] = f2bf(W2[((long)(r * 256 + c)) * 1152 + h * 384 + o] * (1.f / 3.f));
}

// bf2[o2] = sum_o b2[o]*lw2[o][o2] + lb2[o2]   (256 outputs, one wave each)
__global__ __launch_bounds__(256)
void bfold_kernel(const float* __restrict__ b2, const float* __restrict__ lw2,
                  const float* __restrict__ lb2, float* __restrict__ bf2) {
    const int wid = threadIdx.x >> 6, lane = threadIdx.x & 63;
    const int o2 = blockIdx.x * 4 + wid;
    if (o2 >= 256) return;
    float s = 0.f;
    for (int o = lane; o < 384; o += 64) s += b2[o] * lw2[(long)o * 256 + o2];
    s = wave_sum(s);
    if (lane == 0) bf2[o2] = s + lb2[o2];
}

__global__ void g_kernel(const float* __restrict__ le, const float* __restrict__ e,
                         float* __restrict__ g, int ho) {
    int j = blockIdx.x;
    int d = j / 3, h = j % 3;
    float s = 0.f;
    for (int o = threadIdx.x; o < ho; o += 64) s += le[(long)d * ho + o] * e[(long)o * 3 + h];
    s = wave_sum(s);
    if (threadIdx.x == 0) g[j] = s;
}

__global__ void ae_kernel(const float* __restrict__ ea, const float* __restrict__ g,
                          float* __restrict__ aeb, int E) {
    int e = blockIdx.x * 256 + threadIdx.x;
    if (e >= E) return;
    float a[8];
#pragma unroll
    for (int d = 0; d < 8; ++d) a[d] = ea[(long)e * 8 + d];
#pragma unroll
    for (int l = 0; l < 4; ++l) {
#pragma unroll
        for (int h = 0; h < 3; ++h) {
            float s = 0.f;
#pragma unroll
            for (int d = 0; d < 8; ++d) s += a[d] * g[l * 24 + d * 3 + h];
            aeb[((size_t)l * E + e) * 3 + h] = s;
        }
    }
}

// one WAVE per output element; 64-lane coalesced reduce over o
__global__ __launch_bounds__(256)
void wqk_kernel(const float* __restrict__ W, const float* __restrict__ q,
                const float* __restrict__ k, float* __restrict__ Wqk,
                int cin, int ho) {
    const int wid = threadIdx.x >> 6, lane = threadIdx.x & 63;
    const int i = blockIdx.x * 4 + wid;
    if (i >= cin * 24) return;
    int c = i / 24, j = i % 24;
    int r = j / 6, t6 = j % 6;
    const float* v = (t6 < 3) ? q : k;
    int h = t6 % 3;
    const float* wrow = W + ((long)r * cin + c) * ho;
    float s = 0.f;
    for (int o = lane; o < ho; o += 64) s += wrow[o] * v[(long)o * 3 + h];
    s = wave_sum(s);
    if (lane == 0) Wqk[i] = s;
}

__global__ __launch_bounds__(256)
void qk_kernel(const float* __restrict__ h, const float* __restrict__ Wqk,
               float* __restrict__ qkn, int N, int cin) {
    const int wid = threadIdx.x >> 6, lane = threadIdx.x & 63;
    const int n = blockIdx.x * 4 + wid;
    if (n >= N) return;
    float acc[24];
#pragma unroll
    for (int j = 0; j < 24; ++j) acc[j] = 0.f;
    for (int c = lane; c < cin; c += 64) {
        float hv = h[(long)n * cin + c];
        const float* w = Wqk + (long)c * 24;
#pragma unroll
        for (int j = 0; j < 24; ++j) acc[j] += hv * w[j];
    }
#pragma unroll
    for (int j = 0; j < 24; ++j) {
        float v = wave_sum(acc[j]);
        if (lane == 0) qkn[(long)n * 24 + j] = v;
    }
}

// ---------------- cast fp32 -> bf16 ----------------
__global__ void cast_kernel(const float* __restrict__ in, ushort* __restrict__ out, long n) {
    long i = ((long)blockIdx.x * 256 + threadIdx.x) * 4;
    if (i + 4 <= n) {
        float4 v = *(const float4*)(in + i);
        ushort4 o4 = { f2bf(v.x), f2bf(v.y), f2bf(v.z), f2bf(v.w) };
        *(ushort4*)(out + i) = o4;
    } else {
        for (long j = i; j < n; ++j) out[j] = f2bf(in[j]);
    }
}

// ---------------- bf16 MFMA GEMM (2-phase double-buffered) ----------------
// C(M,NCols) = A(M,K) * Bt(NCols,K)^T.  XCD-aware bijective swizzle.
// PARTIAL: split-K — slice = swizzled_tile / nbase, K window [slice*Ks, +Ks),
//          stores fp32 partials (no bias) at Cp + slice*M*NCols.
template<int OUT_BF16, int DUAL, int PARTIAL>
__global__ __launch_bounds__(256, 4)
void gemm_bf16(const ushort* __restrict__ A, const ushort* __restrict__ Bt,
               void* __restrict__ Cp, ushort* __restrict__ C2,
               const float* __restrict__ bias,
               int M, int K, int NCols, int nbn, int nwg, int nbase, int Ks) {
    __shared__ ushort lA[2][128 * 32];
    __shared__ ushort lB[2][128 * 32];
    const int t = threadIdx.x;
    const int lane = t & 63;
    const int wid = t >> 6;

    int b = blockIdx.x;
    int q8 = nwg >> 3, r8 = nwg & 7;
    int xcd = b & 7, loc = b >> 3;
    int tt = (xcd < r8 ? xcd * (q8 + 1) : r8 * (q8 + 1) + (xcd - r8) * q8) + loc;
    const int slice = tt / nbase;
    const int tile = tt % nbase;
    const int kbase = slice * Ks;
    const int bm = (tile / nbn) * 128;
    const int bn = (tile % nbn) * 128;

    const int wr = (wid >> 1) * 64;
    const int wc = (wid & 1) * 64;

    f32x4 acc[4][4];
#pragma unroll
    for (int m = 0; m < 4; ++m)
#pragma unroll
        for (int nn = 0; nn < 4; ++nn) acc[m][nn] = (f32x4){0.f, 0.f, 0.f, 0.f};

    const int sr = t >> 2;
    const int sk = (((t & 3) ^ ((t >> 3) & 3)) * 8);
    long ar0 = bm + sr;      if (ar0 > M - 1) ar0 = M - 1;
    long ar1 = bm + sr + 64; if (ar1 > M - 1) ar1 = M - 1;
    const ushort* gA0 = A + ar0 * K + sk + kbase;
    const ushort* gA1 = A + ar1 * K + sk + kbase;
    const ushort* gB0 = Bt + (long)(bn + sr) * K + sk + kbase;
    const ushort* gB1 = Bt + (long)(bn + sr + 64) * K + sk + kbase;

    const int frow = lane & 15;
    const int pc8 = (((lane >> 4) ^ ((lane >> 1) & 3)) * 8);

    // prologue: stage tile 0 into buffer 0
    GLD_LDS(gA0, &lA[0][t * 8]);
    GLD_LDS(gA1, &lA[0][t * 8 + 64 * 32]);
    GLD_LDS(gB0, &lB[0][t * 8]);
    GLD_LDS(gB1, &lB[0][t * 8 + 64 * 32]);
    __syncthreads();

    int cur = 0;
    for (int k0 = 0; k0 < Ks; k0 += 32) {
        if (k0 + 32 < Ks) {             // stage next tile into the other buffer
            int nb = cur ^ 1, kn = k0 + 32;
            GLD_LDS(gA0 + kn, &lA[nb][t * 8]);
            GLD_LDS(gA1 + kn, &lA[nb][t * 8 + 64 * 32]);
            GLD_LDS(gB0 + kn, &lB[nb][t * 8]);
            GLD_LDS(gB1 + kn, &lB[nb][t * 8 + 64 * 32]);
        }
        bf16x8 af[4], bff[4];
#pragma unroll
        for (int m = 0; m < 4; ++m)
            af[m] = *(const bf16x8*)&lA[cur][(wr + m * 16 + frow) * 32 + pc8];
#pragma unroll
        for (int nn = 0; nn < 4; ++nn)
            bff[nn] = *(const bf16x8*)&lB[cur][(wc + nn * 16 + frow) * 32 + pc8];
#pragma unroll
        for (int m = 0; m < 4; ++m)
#pragma unroll
            for (int nn = 0; nn < 4; ++nn)
                acc[m][nn] = __builtin_amdgcn_mfma_f32_16x16x32_bf16(af[m], bff[nn], acc[m][nn], 0, 0, 0);
        __syncthreads();                // drains vmcnt (stage done) + lgkm; all waves past reads
        cur ^= 1;
    }

    const int crow = (lane >> 4) * 4;
    const int ccol = lane & 15;
#pragma unroll
    for (int m = 0; m < 4; ++m) {
#pragma unroll
        for (int nn = 0; nn < 4; ++nn) {
            int col = bn + wc + nn * 16 + ccol;
            float bv = (!PARTIAL && bias) ? bias[col] : 0.f;
#pragma unroll
            for (int r = 0; r < 4; ++r) {
                int row = bm + wr + m * 16 + crow + r;
                if (row < M) {
                    float v = acc[m][nn][r] + bv;
                    if (PARTIAL) {
                        ((float*)Cp)[(size_t)slice * M * NCols + (long)row * NCols + col] = v;
                    } else {
                        if (OUT_BF16) ((ushort*)Cp)[(long)row * NCols + col] = f2bf(v);
                        else          ((float*)Cp)[(long)row * NCols + col] = v;
                        if (DUAL)     C2[(long)row * NCols + col] = f2bf(v);
                    }
                }
            }
        }
    }
}

// ---------------- split-K reduce: out = sum of 3 partials + bias (fp32 + bf16) ----------------
__global__ void reduce3_kernel(const float* __restrict__ P, const float* __restrict__ bias,
                               float* __restrict__ outf, ushort* __restrict__ outb, int M) {
    long i = (long)blockIdx.x * 256 + threadIdx.x;
    long total = (long)M * 64;
    if (i >= total) return;
    long off = i * 4;
    int col = (int)(off & 255);
    const long stride = (long)M * 256;
    float4 a = *(const float4*)(P + off);
    float4 b = *(const float4*)(P + stride + off);
    float4 c = *(const float4*)(P + 2 * stride + off);
    float4 bs = *(const float4*)(bias + col);
    float4 r = { a.x + b.x + c.x + bs.x, a.y + b.y + c.y + bs.y,
                 a.z + b.z + c.z + bs.z, a.w + b.w + c.w + bs.w };
    *(float4*)(outf + off) = r;
    ushort4 o4 = { f2bf(r.x), f2bf(r.y), f2bf(r.z), f2bf(r.w) };
    *(ushort4*)(outb + off) = o4;
}

// ---------------- attention + aggregate (layers 1,3,4: one wave per node) ----------------
template<int CP, int OO>
__global__ __launch_bounds__(256)
void attn_kernel(const float* __restrict__ qkn, const ushort* __restrict__ xW,
                 const float* __restrict__ ae, const int* __restrict__ offs,
                 const int* __restrict__ csr, const int* __restrict__ srcv,
                 const int* __restrict__ etv, const float* __restrict__ bias,
                 ushort* __restrict__ out, int N) {
    __shared__ float p_sh[4][64][3];
    __shared__ int   m_sh[4][64];
    __shared__ float red[4][CP * 128];
    const int wid = threadIdx.x >> 6, lane = threadIdx.x & 63;
    const int n = blockIdx.x * 4 + wid;
    if (n >= N) return;
    const int e0 = offs[n];
    const int deg = offs[n + 1] - e0;
    const float* qd = qkn + (long)n * 24;

    float m0 = -1e30f, m1 = -1e30f, m2 = -1e30f;
    for (int base = 0; base < deg; base += 64) {
        int idx = base + lane;
        if (idx < deg) {
            int eid = csr[e0 + idx];
            int s_ = srcv[eid], t_ = etv[eid];
            const float* qs = qkn + (long)s_ * 24 + t_ * 6;
            const float* a3 = ae + (long)eid * 3;
            float v0 = qd[t_ * 6 + 0] + qs[3] + a3[0];
            float v1 = qd[t_ * 6 + 1] + qs[4] + a3[1];
            float v2 = qd[t_ * 6 + 2] + qs[5] + a3[2];
            v0 = v0 > 0.f ? v0 : 0.2f * v0;
            v1 = v1 > 0.f ? v1 : 0.2f * v1;
            v2 = v2 > 0.f ? v2 : 0.2f * v2;
            m0 = fmaxf(m0, v0); m1 = fmaxf(m1, v1); m2 = fmaxf(m2, v2);
        }
    }
    m0 = wave_max(m0); m1 = wave_max(m1); m2 = wave_max(m2);

    float acc[2 * CP];
#pragma unroll
    for (int i = 0; i < 2 * CP; ++i) acc[i] = 0.f;
    float ps0 = 0.f, ps1 = 0.f, ps2 = 0.f;

    for (int base = 0; base < deg; base += 64) {
        int cnt2 = deg - base; if (cnt2 > 64) cnt2 = 64;
        if (lane < cnt2) {
            int eid = csr[e0 + base + lane];
            int s_ = srcv[eid], t_ = etv[eid];
            const float* qs = qkn + (long)s_ * 24 + t_ * 6;
            const float* a3 = ae + (long)eid * 3;
            float v0 = qd[t_ * 6 + 0] + qs[3] + a3[0];
            float v1 = qd[t_ * 6 + 1] + qs[4] + a3[1];
            float v2 = qd[t_ * 6 + 2] + qs[5] + a3[2];
            v0 = v0 > 0.f ? v0 : 0.2f * v0;
            v1 = v1 > 0.f ? v1 : 0.2f * v1;
            v2 = v2 > 0.f ? v2 : 0.2f * v2;
            float p0 = __expf(v0 - m0), p1 = __expf(v1 - m1), p2 = __expf(v2 - m2);
            p_sh[wid][lane][0] = p0; p_sh[wid][lane][1] = p1; p_sh[wid][lane][2] = p2;
            m_sh[wid][lane] = (s_ * 4 + t_) * (CP * 128);
            ps0 += p0; ps1 += p1; ps2 += p2;
        }
        wave_sync();
        for (int j = 0; j < cnt2; ++j) {
            int xb = m_sh[wid][j];
            float pp0 = p_sh[wid][j][0], pp1 = p_sh[wid][j][1], pp2 = p_sh[wid][j][2];
            const uint* xr = (const uint*)(xW + xb);
#pragma unroll
            for (int ii = 0; ii < CP; ++ii) {
                uint v = xr[lane + 64 * ii];
                const int hh = (ii * 128) / OO;
                float p = (hh == 0) ? pp0 : (hh == 1 ? pp1 : pp2);
                acc[2 * ii]     += p * bf2f((ushort)(v & 0xffffu));
                acc[2 * ii + 1] += p * bf2f((ushort)(v >> 16));
            }
        }
        wave_sync();
    }
    ps0 = wave_sum(ps0); ps1 = wave_sum(ps1); ps2 = wave_sum(ps2);
    float i0 = 1.f / fmaxf(ps0, 1e-16f);
    float i1 = 1.f / fmaxf(ps1, 1e-16f);
    float i2 = 1.f / fmaxf(ps2, 1e-16f);
#pragma unroll
    for (int ii = 0; ii < CP; ++ii) {
        const int hh = (ii * 128) / OO;
        float iv = (hh == 0) ? i0 : (hh == 1 ? i1 : i2);
        red[wid][128 * ii + 2 * lane]     = acc[2 * ii] * iv;
        red[wid][128 * ii + 2 * lane + 1] = acc[2 * ii + 1] * iv;
    }
    wave_sync();
    for (int o = lane; o < OO; o += 64) {
        float v = (red[wid][o] + red[wid][OO + o] + red[wid][2 * OO + o]) * (1.f / 3.f) + bias[o];
        out[(long)n * OO + o] = f2bf(v);
    }
}

// ---------------- layer-2 attention: Z-accumulation (one wave per node) ----------------
#define UPD(R) { \
    acc[0][R][0] += pk.x * x0; acc[0][R][1] += pk.x * x1; acc[0][R][2] += pk.x * x2; acc[0][R][3] += pk.x * x3; \
    acc[1][R][0] += pk.y * x0; acc[1][R][1] += pk.y * x1; acc[1][R][2] += pk.y * x2; acc[1][R][3] += pk.y * x3; \
    acc[2][R][0] += pk.z * x0; acc[2][R][1] += pk.z * x1; acc[2][R][2] += pk.z * x2; acc[2][R][3] += pk.z * x3; }

__global__ __launch_bounds__(256)
void attn2_kernel(const float* __restrict__ qkn, const ushort* __restrict__ hbf,
                  const float* __restrict__ ae, const int* __restrict__ offs,
                  const int* __restrict__ csr, const int* __restrict__ srcv,
                  const int* __restrict__ etv, ushort* __restrict__ Z, int N) {
    __shared__ float4 pk_sh[4][64];
    const int wid = threadIdx.x >> 6, lane = threadIdx.x & 63;
    const int n = blockIdx.x * 4 + wid;
    if (n >= N) return;
    const int e0 = offs[n];
    const int deg = offs[n + 1] - e0;
    const float* qd = qkn + (long)n * 24;

    float m0 = -1e30f, m1 = -1e30f, m2 = -1e30f;
    for (int base = 0; base < deg; base += 64) {
        int idx = base + lane;
        if (idx < deg) {
            int eid = csr[e0 + idx];
            int s_ = srcv[eid], t_ = etv[eid];
            const float* qs = qkn + (long)s_ * 24 + t_ * 6;
            const float* a3 = ae + (long)eid * 3;
            float v0 = qd[t_ * 6 + 0] + qs[3] + a3[0];
            float v1 = qd[t_ * 6 + 1] + qs[4] + a3[1];
            float v2 = qd[t_ * 6 + 2] + qs[5] + a3[2];
            v0 = v0 > 0.f ? v0 : 0.2f * v0;
            v1 = v1 > 0.f ? v1 : 0.2f * v1;
            v2 = v2 > 0.f ? v2 : 0.2f * v2;
            m0 = fmaxf(m0, v0); m1 = fmaxf(m1, v1); m2 = fmaxf(m2, v2);
        }
    }
    m0 = wave_max(m0); m1 = wave_max(m1); m2 = wave_max(m2);

    float acc[3][4][4];
#pragma unroll
    for (int h = 0; h < 3; ++h)
#pragma unroll
        for (int r = 0; r < 4; ++r)
#pragma unroll
            for (int c = 0; c < 4; ++c) acc[h][r][c] = 0.f;
    float ps0 = 0.f, ps1 = 0.f, ps2 = 0.f;

    for (int base = 0; base < deg; base += 64) {
        int cnt2 = deg - base; if (cnt2 > 64) cnt2 = 64;
        if (lane < cnt2) {
            int eid = csr[e0 + base + lane];
            int s_ = srcv[eid], t_ = etv[eid];
            const float* qs = qkn + (long)s_ * 24 + t_ * 6;
            const float* a3 = ae + (long)eid * 3;
            float v0 = qd[t_ * 6 + 0] + qs[3] + a3[0];
            float v1 = qd[t_ * 6 + 1] + qs[4] + a3[1];
            float v2 = qd[t_ * 6 + 2] + qs[5] + a3[2];
            v0 = v0 > 0.f ? v0 : 0.2f * v0;
            v1 = v1 > 0.f ? v1 : 0.2f * v1;
            v2 = v2 > 0.f ? v2 : 0.2f * v2;
            float p0 = __expf(v0 - m0), p1 = __expf(v1 - m1), p2 = __expf(v2 - m2);
            pk_sh[wid][lane] = make_float4(p0, p1, p2,
                                           __int_as_float((s_ << 2) | t_));
            ps0 += p0; ps1 += p1; ps2 += p2;
        }
        wave_sync();
        for (int j = 0; j < cnt2; ++j) {
            float4 pk = pk_sh[wid][j];
            int pack = __float_as_int(pk.w);
            int r_ = pack & 3;
            const uint2 v = *(const uint2*)(hbf + ((long)(pack >> 2)) * 256 + lane * 4);
            float x0 = bf2f((ushort)(v.x & 0xffffu)), x1 = bf2f((ushort)(v.x >> 16));
            float x2 = bf2f((ushort)(v.y & 0xffffu)), x3 = bf2f((ushort)(v.y >> 16));
            if (r_ == 0)      UPD(0)
            else if (r_ == 1) UPD(1)
            else if (r_ == 2) UPD(2)
            else              UPD(3)
        }
        wave_sync();
    }
    ps0 = wave_sum(ps0); ps1 = wave_sum(ps1); ps2 = wave_sum(ps2);
    float inv[3];
    inv[0] = 1.f / fmaxf(ps0, 1e-16f);
    inv[1] = 1.f / fmaxf(ps1, 1e-16f);
    inv[2] = 1.f / fmaxf(ps2, 1e-16f);
    ushort* zr = Z + (long)n * 3072 + lane * 4;
#pragma unroll
    for (int h = 0; h < 3; ++h) {
#pragma unroll
        for (int r = 0; r < 4; ++r) {
            ushort4 o4 = { f2bf(acc[h][r][0] * inv[h]), f2bf(acc[h][r][1] * inv[h]),
                           f2bf(acc[h][r][2] * inv[h]), f2bf(acc[h][r][3] * inv[h]) };
            *(ushort4*)(zr + h * 1024 + r * 256) = o4;
        }
    }
}

// ---------------- final: hole-node softmax ----------------
__global__ void softmax_kernel(const float* __restrict__ h, const int* __restrict__ hole,
                               float* __restrict__ out, int B) {
    int b = blockIdx.x;
    int t = threadIdx.x;
    int lane = t & 63, wid = t >> 6;
    __shared__ float sm[4];
    __shared__ float ss[4];
    int row = hole[b];
    float v = h[(long)row * 256 + t];
    float m = v;
#pragma unroll
    for (int d = 32; d >= 1; d >>= 1) m = fmaxf(m, __shfl_xor(m, d));
    if (lane == 0) sm[wid] = m;
    __syncthreads();
    m = fmaxf(fmaxf(sm[0], sm[1]), fmaxf(sm[2], sm[3]));
    float ex = __expf(v - m);
    float s = ex;
#pragma unroll
    for (int d = 32; d >= 1; d >>= 1) s += __shfl_xor(s, d);
    if (lane == 0) ss[wid] = s;
    __syncthreads();
    s = ss[0] + ss[1] + ss[2] + ss[3];
    out[(long)b * 256 + t] = ex / s;
}

// ---------------- host ----------------
extern "C" void kernel_launch(void* const* d_in, const int* in_sizes, int n_in,
                              void* d_out, int out_size, void* d_ws, size_t ws_size,
                              hipStream_t stream) {
    const float* x   = (const float*)d_in[0];
    const int*   ei  = (const int*)d_in[1];
    const int*   ety = (const int*)d_in[2];
    const float* ea  = (const float*)d_in[3];
    const int*   bat = (const int*)d_in[4];

    const int N = in_sizes[0] / 768;
    const int E = in_sizes[2];
    const int B = out_size / 256;

    static const int CIN[4]  = {768, 256, 256, 256};
    static const int COUT[4] = {128, 384, 128, 128};
    static const int HO[4]   = {384, 1152, 384, 384};
    static const int NCC[4]  = {1536, 4608, 1536, 1536};

    const float *Wp[4], *qp[4], *kp[4], *lep[4], *ep[4], *bp[4], *lwp[4], *lbp[4];
    for (int l = 0; l < 4; ++l) {
        Wp[l]  = (const float*)d_in[5 + 6 * l];
        qp[l]  = (const float*)d_in[6 + 6 * l];
        kp[l]  = (const float*)d_in[7 + 6 * l];
        lep[l] = (const float*)d_in[8 + 6 * l];
        ep[l]  = (const float*)d_in[9 + 6 * l];
        bp[l]  = (const float*)d_in[10 + 6 * l];
        lwp[l] = (const float*)d_in[29 + 2 * l];
        lbp[l] = (const float*)d_in[30 + 2 * l];
    }

    char* ws = (char*)d_ws;
    size_t pos = 0;
    auto carve = [&](size_t bytes) -> char* {
        char* r = ws + pos;
        pos += (bytes + 255) & ~(size_t)255;
        return r;
    };
    ushort *Wt[4], *lwT[4];
    float* Wqk[4];
    for (int l = 0; l < 4; ++l) Wt[l]  = (ushort*)carve(l == 1 ? 0 : (size_t)2 * NCC[l] * CIN[l]);
    for (int l = 0; l < 4; ++l) lwT[l] = (ushort*)carve((size_t)2 * 256 * COUT[l]);
    for (int l = 0; l < 4; ++l) Wqk[l] = (float*)carve((size_t)4 * 24 * CIN[l]);
    float*  gbuf  = (float*)carve(4 * 24 * 4);
    float*  aeb   = (float*)carve((size_t)4 * E * 3 * 4);
    float*  qkn   = (float*)carve((size_t)N * 24 * 4);
    ushort* hbf   = (ushort*)carve((size_t)N * 768 * 2);
    ushort* xWb   = (ushort*)carve((size_t)N * 1536 * 2);   // also: layer-2 split-K fp32 partials (3 * N*256*4 bytes == N*1536*2)
    ushort* Zb    = (ushort*)carve((size_t)N * 3072 * 2);
    ushort* A2    = (ushort*)carve((size_t)3072 * 384 * 2);
    ushort* W2T   = (ushort*)carve((size_t)256 * 3072 * 2);
    float*  bf2   = (float*)carve(256 * 4);
    ushort* convbf= (ushort*)carve((size_t)N * 384 * 2);
    float*  hbuf  = (float*)carve((size_t)N * 256 * 4);
    int* cnt  = (int*)carve((size_t)N * 4);
    int* offs = (int*)carve((size_t)(N + 1) * 4);
    int* cur  = (int*)carve((size_t)N * 4);
    int* csr  = (int*)carve((size_t)E * 4);
    int* hole = (int*)carve((size_t)B * 4);

    hipMemsetAsync(cnt, 0, (size_t)N * 4, stream);
    hipMemsetAsync(cur, 0, (size_t)N * 4, stream);
    hipMemsetAsync(hole, 0x7f, (size_t)B * 4, stream);

    const int* dst = ei + E;
    deg_kernel<<<(E + 255) / 256, 256, 0, stream>>>(dst, cnt, E);
    scan_kernel<<<1, 1024, 0, stream>>>(cnt, offs, N);
    fill_kernel<<<(E + 255) / 256, 256, 0, stream>>>(dst, offs, cur, csr, E);
    hole_kernel<<<(N + 255) / 256, 256, 0, stream>>>(bat, hole, N);

    for (int l = 0; l < 4; ++l) {
        if (l != 1) {
            long tw = (long)NCC[l] * CIN[l];
            trW_kernel<<<(int)((tw + 255) / 256), 256, 0, stream>>>(Wp[l], Wt[l], CIN[l], HO[l], tw);
        }
        long tl = 256L * COUT[l];
        trLw_kernel<<<(int)((tl + 255) / 256), 256, 0, stream>>>(lwp[l], lwT[l], COUT[l], tl);
        g_kernel<<<24, 64, 0, stream>>>(lep[l], ep[l], gbuf + l * 24, HO[l]);
        wqk_kernel<<<(CIN[l] * 24 + 3) / 4, 256, 0, stream>>>(Wp[l], qp[l], kp[l], Wqk[l], CIN[l], HO[l]);
    }
    // layer-2 fold: W2T(256,3072) = lwT2(256,384) @ A2(3072,384)^T ; bf2 = b2@lw2 + lb2
    a2_kernel<<<(int)((3072L * 384 + 255) / 256), 256, 0, stream>>>(Wp[1], A2);
    gemm_bf16<1, 0, 0><<<48, 256, 0, stream>>>(lwT[1], A2, (void*)W2T, nullptr, nullptr,
                                               256, 384, 3072, 24, 48, 48, 384);
    bfold_kernel<<<64, 256, 0, stream>>>(bp[1], lwp[1], lbp[1], bf2);
    ae_kernel<<<(E + 255) / 256, 256, 0, stream>>>(ea, gbuf, aeb, E);

    const int nbm = (N + 127) / 128;
    for (int l = 0; l < 4; ++l) {
        const float* hin = (l == 0) ? x : hbuf;
        if (l == 0) {
            long hc = (long)N * 768;
            cast_kernel<<<(int)((hc / 4 + 255) / 256), 256, 0, stream>>>(x, hbf, hc);
        }
        qk_kernel<<<(N + 3) / 4, 256, 0, stream>>>(hin, Wqk[l], qkn, N, CIN[l]);
        if (l == 1) {
            attn2_kernel<<<(N + 3) / 4, 256, 0, stream>>>(qkn, hbf, aeb + (size_t)l * E * 3,
                                                          offs, csr, ei, ety, Zb, N);
            // split-K=3 GEMM: Zb(N,3072) @ W2T(256,3072)^T -> fp32 partials in xWb
            int nbase = nbm * 2, nwgS = nbase * 3;
            gemm_bf16<0, 0, 1><<<nwgS, 256, 0, stream>>>(Zb, W2T, (void*)xWb, nullptr, nullptr,
                                                         N, 3072, 256, 2, nwgS, nbase, 1024);
            reduce3_kernel<<<(int)(((long)N * 64 + 255) / 256), 256, 0, stream>>>(
                (const float*)xWb, bf2, hbuf, hbf, N);
        } else {
            int nbn1 = NCC[l] / 128, nwg1 = nbm * nbn1;
            gemm_bf16<1, 0, 0><<<nwg1, 256, 0, stream>>>(hbf, Wt[l], (void*)xWb, nullptr, nullptr,
                                                         N, CIN[l], NCC[l], nbn1, nwg1, nwg1, CIN[l]);
            attn_kernel<3, 128><<<(N + 3) / 4, 256, 0, stream>>>(qkn, xWb, aeb + (size_t)l * E * 3,
                                                                 offs, csr, ei, ety, bp[l], convbf, N);
            int nwg2 = nbm * 2;
            gemm_bf16<0, 1, 0><<<nwg2, 256, 0, stream>>>(convbf, lwT[l], (void*)hbuf, hbf, lbp[l],
                                                         N, COUT[l], 256, 2, nwg2, nwg2, COUT[l]);
        }
    }
    softmax_kernel<<<B, 256, 0, stream>>>(hbuf, hole, (float*)d_out, B);
}